// Round 6
// baseline (49.462 us; speedup 1.0000x reference)
//
#include <hip/hip_runtime.h>

// Problem constants (match the JAX reference)
constexpr int T_LEN  = 1000;   // B*T, B=1
constexpr int NBKG   = 100;    // background units
constexpr int NV1    = 50000;
constexpr int NLM    = 10000;
constexpr int NPOST  = NV1 + NLM;   // 60000
constexpr int CONN   = 4;

constexpr int TCHUNK = 40;     // t steps per block (25 chunks of 40 = 1000)
constexpr int NPT    = 4;      // neurons per thread (float4 store)
constexpr int BLOCK  = 256;
constexpr int NPB    = BLOCK * NPT;  // 1024 neurons per block
constexpr int TSTRIDE = 40;    // t-stride in halves. 40*2=80 B (16B-aligned);
                               // b128 start dword = 20c+4i mod 32 -> 8 start
                               // classes x 4 banks = all 32 banks tiled.

typedef _Float16 half8 __attribute__((ext_vector_type(8)));
typedef float    f32x4 __attribute__((ext_vector_type(4)));

__global__ __launch_bounds__(BLOCK)
void bkg_noise_kernel(const float* __restrict__ rest,      // [T_LEN, NBKG]
                      const float* __restrict__ v1_w,      // [NV1*CONN]
                      const int*   __restrict__ v1_c,      // [NV1*CONN]
                      const float* __restrict__ lm_w,      // [NLM*CONN]
                      const int*   __restrict__ lm_c,      // [NLM*CONN]
                      float* __restrict__ out)             // [T_LEN, NPOST]
{
    // Transposed fp16 rest tile: s_restT[c * TSTRIDE + t] = (half)rest[t0+t][c]
    // Poisson counts are small integers -> exact in fp16.
    __shared__ _Float16 s_restT[NBKG * TSTRIDE];   // 8 KB

    const int t0 = blockIdx.y * TCHUNK;

    // Stage + transpose + f32->f16 convert. Global reads coalesced.
    for (int idx = threadIdx.x; idx < TCHUNK * NBKG; idx += BLOCK) {
        const int t = idx / NBKG;
        const int c = idx - t * NBKG;
        s_restT[c * TSTRIDE + t] = (_Float16)rest[(size_t)(t0 + t) * NBKG + c];
    }
    __syncthreads();

    const int n0 = blockIdx.x * NPB + threadIdx.x * NPT;
    if (n0 >= NPOST) return;

    // 50000 % 4 == 0 -> a thread's 4 neurons never straddle the v1/lm split.
    const float* wp;
    const int*   cp;
    if (n0 < NV1) { wp = v1_w + (size_t)n0 * CONN;          cp = v1_c + (size_t)n0 * CONN; }
    else          { wp = lm_w + (size_t)(n0 - NV1) * CONN;  cp = lm_c + (size_t)(n0 - NV1) * CONN; }

    // 16 contiguous weights + 16 contiguous cols per thread (coalesced across lanes).
    float wv[NPT * CONN];
    int   boff[NPT * CONN];    // precomputed LDS half-offsets: col * TSTRIDE
    {
        const float4* w4 = reinterpret_cast<const float4*>(wp);
        const int4*   c4 = reinterpret_cast<const int4*>(cp);
        #pragma unroll
        for (int i = 0; i < NPT; ++i) {
            float4 w = w4[i];
            int4   c = c4[i];
            wv[i*4+0] = w.x; wv[i*4+1] = w.y; wv[i*4+2] = w.z; wv[i*4+3] = w.w;
            boff[i*4+0] = c.x * TSTRIDE;
            boff[i*4+1] = c.y * TSTRIDE;
            boff[i*4+2] = c.z * TSTRIDE;
            boff[i*4+3] = c.w * TSTRIDE;
        }
    }

    // Main loop: 8 t-values per ds_read_b128 (fp16 column-major rest tile).
    #pragma unroll
    for (int t8 = 0; t8 < TCHUNK / 8; ++t8) {
        float acc[8][NPT];   // [t_sub][neuron]
        #pragma unroll
        for (int j = 0; j < NPT; ++j) {
            const half8 r0 = *reinterpret_cast<const half8*>(&s_restT[boff[j*4+0] + t8*8]);
            const half8 r1 = *reinterpret_cast<const half8*>(&s_restT[boff[j*4+1] + t8*8]);
            const half8 r2 = *reinterpret_cast<const half8*>(&s_restT[boff[j*4+2] + t8*8]);
            const half8 r3 = *reinterpret_cast<const half8*>(&s_restT[boff[j*4+3] + t8*8]);
            const float w0 = wv[j*4+0], w1 = wv[j*4+1], w2 = wv[j*4+2], w3 = wv[j*4+3];
            #pragma unroll
            for (int t = 0; t < 8; ++t) {
                float acc_t = w0 * (float)r0[t];
                acc_t = fmaf(w1, (float)r1[t], acc_t);
                acc_t = fmaf(w2, (float)r2[t], acc_t);
                acc_t = fmaf(w3, (float)r3[t], acc_t);
                acc[t][j] = acc_t;
            }
        }
        #pragma unroll
        for (int t = 0; t < 8; ++t) {
            f32x4 o = { acc[t][0], acc[t][1], acc[t][2], acc[t][3] };
            // Non-temporal: stream past L2, don't evict the weight/rest set.
            __builtin_nontemporal_store(
                o, reinterpret_cast<f32x4*>(out + (size_t)(t0 + t8*8 + t) * NPOST + n0));
        }
    }
}

extern "C" void kernel_launch(void* const* d_in, const int* in_sizes, int n_in,
                              void* d_out, int out_size, void* d_ws, size_t ws_size,
                              hipStream_t stream) {
    // setup_inputs order: rest, v1_weights, v1_rows, v1_cols, lm_weights, lm_rows, lm_cols
    const float* rest = (const float*)d_in[0];
    const float* v1_w = (const float*)d_in[1];
    // d_in[2] = v1_rows (implicit: repeat(arange(NV1), CONN)) -- unused
    const int*   v1_c = (const int*)d_in[3];
    const float* lm_w = (const float*)d_in[4];
    // d_in[5] = lm_rows -- unused
    const int*   lm_c = (const int*)d_in[6];
    float* out = (float*)d_out;

    dim3 grid((NPOST + NPB - 1) / NPB, T_LEN / TCHUNK);  // 59 x 25
    bkg_noise_kernel<<<grid, BLOCK, 0, stream>>>(rest, v1_w, v1_c, lm_w, lm_c, out);
}

// Round 7
// 43.958 us; speedup vs baseline: 1.1252x; 1.1252x over previous
//
#include <hip/hip_runtime.h>

// Problem constants (match the JAX reference)
constexpr int T_LEN  = 1000;   // B*T, B=1
constexpr int NBKG   = 100;    // background units
constexpr int NV1    = 50000;
constexpr int NLM    = 10000;
constexpr int NPOST  = NV1 + NLM;   // 60000
constexpr int CONN   = 4;

constexpr int TCHUNK = 40;     // t steps per chunk (25 chunks of 40 = 1000)
constexpr int NCH    = 25;     // total t-chunks
constexpr int YB     = 13;     // grid.y; block y handles chunks y and y+13
constexpr int NPT    = 4;      // neurons per thread (float4 store)
constexpr int BLOCK  = 256;
constexpr int NPB    = BLOCK * NPT;  // 1024 neurons per block
constexpr int TSTRIDE = 40;    // t-stride in halves (80 B, 16B-aligned; b128
                               // start class 20c+4i mod 32 -> all 32 banks)
constexpr int LDF    = 16;     // floats staged per thread (250 threads active)

typedef _Float16 half8 __attribute__((ext_vector_type(8)));

__global__ __launch_bounds__(BLOCK)
void bkg_noise_kernel(const float* __restrict__ rest,      // [T_LEN, NBKG]
                      const float* __restrict__ v1_w,      // [NV1*CONN]
                      const int*   __restrict__ v1_c,      // [NV1*CONN]
                      const float* __restrict__ lm_w,      // [NLM*CONN]
                      const int*   __restrict__ lm_c,      // [NLM*CONN]
                      float* __restrict__ out)             // [T_LEN, NPOST]
{
    // Transposed fp16 rest tile: s_restT[c * TSTRIDE + t] (Poisson counts exact in fp16)
    __shared__ _Float16 s_restT[NBKG * TSTRIDE];   // 8 KB

    const int tid = threadIdx.x;
    const int n0  = blockIdx.x * NPB + tid * NPT;
    const bool active = (n0 < NPOST);
    const int n0c = active ? n0 : 0;   // clamped for safe loads

    // ---- weights/cols: loaded ONCE per block (was once per t-chunk) ----
    const float* wp;
    const int*   cp;
    if (n0c < NV1) { wp = v1_w + (size_t)n0c * CONN;          cp = v1_c + (size_t)n0c * CONN; }
    else           { wp = lm_w + (size_t)(n0c - NV1) * CONN;  cp = lm_c + (size_t)(n0c - NV1) * CONN; }

    float wv[NPT * CONN];
    int   boff[NPT * CONN];
    {
        const float4* w4 = reinterpret_cast<const float4*>(wp);
        const int4*   c4 = reinterpret_cast<const int4*>(cp);
        #pragma unroll
        for (int i = 0; i < NPT; ++i) {
            float4 w = w4[i];
            int4   c = c4[i];
            wv[i*4+0] = w.x; wv[i*4+1] = w.y; wv[i*4+2] = w.z; wv[i*4+3] = w.w;
            boff[i*4+0] = c.x * TSTRIDE;
            boff[i*4+1] = c.y * TSTRIDE;
            boff[i*4+2] = c.z * TSTRIDE;
            boff[i*4+3] = c.w * TSTRIDE;
        }
    }

    // ---- reg-staged rest chunk (T14 issue-early / write-late split) ----
    float sreg[LDF];
    const bool stager = (tid * LDF < TCHUNK * NBKG);   // threads 0..249

    // load chunk y into registers
    {
        const float* base = rest + (size_t)blockIdx.y * TCHUNK * NBKG + tid * LDF;
        if (stager) {
            #pragma unroll
            for (int q = 0; q < LDF / 4; ++q) {
                float4 v = *reinterpret_cast<const float4*>(base + q * 4);
                sreg[q*4+0] = v.x; sreg[q*4+1] = v.y; sreg[q*4+2] = v.z; sreg[q*4+3] = v.w;
            }
        }
    }

    for (int ci = blockIdx.y, it = 0; ci < NCH; ci += YB, ++it) {
        if (it > 0) __syncthreads();   // all reads of LDS from previous chunk done

        // regs -> LDS, transposed + f32->f16
        if (stager) {
            #pragma unroll
            for (int j = 0; j < LDF; ++j) {
                const int f = tid * LDF + j;
                const int t = f / NBKG;
                const int c = f - t * NBKG;
                s_restT[c * TSTRIDE + t] = (_Float16)sreg[j];
            }
        }
        __syncthreads();

        // issue next chunk's global loads NOW; latency hides under compute+stores
        const int cn = ci + YB;
        if (cn < NCH && stager) {
            const float* base = rest + (size_t)cn * TCHUNK * NBKG + tid * LDF;
            #pragma unroll
            for (int q = 0; q < LDF / 4; ++q) {
                float4 v = *reinterpret_cast<const float4*>(base + q * 4);
                sreg[q*4+0] = v.x; sreg[q*4+1] = v.y; sreg[q*4+2] = v.z; sreg[q*4+3] = v.w;
            }
        }

        // ---- main compute + store for chunk ci ----
        if (active) {
            const int t0 = ci * TCHUNK;
            #pragma unroll
            for (int t8 = 0; t8 < TCHUNK / 8; ++t8) {
                float acc[8][NPT];
                #pragma unroll
                for (int j = 0; j < NPT; ++j) {
                    const half8 r0 = *reinterpret_cast<const half8*>(&s_restT[boff[j*4+0] + t8*8]);
                    const half8 r1 = *reinterpret_cast<const half8*>(&s_restT[boff[j*4+1] + t8*8]);
                    const half8 r2 = *reinterpret_cast<const half8*>(&s_restT[boff[j*4+2] + t8*8]);
                    const half8 r3 = *reinterpret_cast<const half8*>(&s_restT[boff[j*4+3] + t8*8]);
                    const float w0 = wv[j*4+0], w1 = wv[j*4+1], w2 = wv[j*4+2], w3 = wv[j*4+3];
                    #pragma unroll
                    for (int t = 0; t < 8; ++t) {
                        float a = w0 * (float)r0[t];
                        a = fmaf(w1, (float)r1[t], a);
                        a = fmaf(w2, (float)r2[t], a);
                        a = fmaf(w3, (float)r3[t], a);
                        acc[t][j] = a;
                    }
                }
                #pragma unroll
                for (int t = 0; t < 8; ++t) {
                    float4 o = make_float4(acc[t][0], acc[t][1], acc[t][2], acc[t][3]);
                    *reinterpret_cast<float4*>(out + (size_t)(t0 + t8*8 + t) * NPOST + n0) = o;
                }
            }
        }
    }
}

extern "C" void kernel_launch(void* const* d_in, const int* in_sizes, int n_in,
                              void* d_out, int out_size, void* d_ws, size_t ws_size,
                              hipStream_t stream) {
    // setup_inputs order: rest, v1_weights, v1_rows, v1_cols, lm_weights, lm_rows, lm_cols
    const float* rest = (const float*)d_in[0];
    const float* v1_w = (const float*)d_in[1];
    // d_in[2] = v1_rows (implicit) -- unused
    const int*   v1_c = (const int*)d_in[3];
    const float* lm_w = (const float*)d_in[4];
    // d_in[5] = lm_rows -- unused
    const int*   lm_c = (const int*)d_in[6];
    float* out = (float*)d_out;

    dim3 grid((NPOST + NPB - 1) / NPB, YB);  // 59 x 13; block y does chunks y, y+13
    bkg_noise_kernel<<<grid, BLOCK, 0, stream>>>(rest, v1_w, v1_c, lm_w, lm_c, out);
}